// Round 5
// baseline (102.897 us; speedup 1.0000x reference)
//
#include <hip/hip_runtime.h>
#include <hip/hip_bf16.h>

// ---- problem constants ----
#define BATCH   4096
#define FEAT    1024
#define NTREES  10
#define NNODES  255
#define NLEAF   256
#define NCLS    1000
#define KTOT    (NTREES*NLEAF) // 2560 = GEMM2 K

typedef __attribute__((ext_vector_type(8))) short  bf16x8;
typedef __attribute__((ext_vector_type(4))) float  f32x4;

// workspace layout (bytes)
#define OFF_XB 0u
#define OFF_WT 8388608u
#define OFF_PT 13631488u
#define OFF_RT 18874368u

#define WAITVM(N) asm volatile("s_waitcnt vmcnt(" #N ")" ::: "memory")
#define WAITLGKM() asm volatile("s_waitcnt lgkmcnt(0)" ::: "memory")
#define BAR() __builtin_amdgcn_s_barrier()

__device__ __forceinline__ void load_lds16(const void* g, void* l) {
    __builtin_amdgcn_global_load_lds(
        (const __attribute__((address_space(1))) unsigned int*)g,
        (__attribute__((address_space(3))) unsigned int*)l, 16, 0, 0);
}

// ---------------- fused conversion kernel ----------------
// blocks 0..4095: x -> bf16 ; 4096..6655: w transpose ; 6656..9215: p transpose
__global__ void k_cvt_all(const float* __restrict__ x, const float* __restrict__ w,
                          const float* __restrict__ p,
                          __hip_bfloat16* __restrict__ xb,
                          __hip_bfloat16* __restrict__ wT,
                          __hip_bfloat16* __restrict__ pT) {
    __shared__ float tile[32][33];
    const int bid = blockIdx.x;
    const int tid = threadIdx.x;

    if (bid < 4096) {
        int i = bid * 256 + tid;
        float4 v = reinterpret_cast<const float4*>(x)[i];
        union { ushort4 u; __hip_bfloat16 h[4]; } o;
        o.h[0] = __float2bfloat16(v.x);
        o.h[1] = __float2bfloat16(v.y);
        o.h[2] = __float2bfloat16(v.z);
        o.h[3] = __float2bfloat16(v.w);
        reinterpret_cast<ushort4*>(xb)[i] = o.u;
    } else if (bid < 6656) {
        int idx = bid - 4096;              // 2560: t(10) x fb(32) x nb(8)
        int t  = idx >> 8;
        int fb = ((idx >> 3) & 31) * 32;
        int nb = (idx & 7) * 32;
        int tx = tid & 31, ty = tid >> 5;
#pragma unroll
        for (int j = 0; j < 4; ++j) {
            int f = fb + ty + j * 8;
            int n = nb + tx;
            float v = (n < NNODES) ? w[((size_t)t * FEAT + f) * NNODES + n] : 0.f;
            tile[ty + j * 8][tx] = v;
        }
        __syncthreads();
#pragma unroll
        for (int j = 0; j < 4; ++j) {
            int n = nb + ty + j * 8;
            int f = fb + tx;
            wT[((size_t)t * NLEAF + n) * FEAT + f] = __float2bfloat16(tile[tx][ty + j * 8]);
        }
    } else {
        int idx = bid - 6656;              // 2560: kb(80) x cb(32)
        int cb = (idx & 31) * 32;
        int kb = (idx >> 5) * 32;
        int tx = tid & 31, ty = tid >> 5;
#pragma unroll
        for (int j = 0; j < 4; ++j) {
            int k = kb + ty + j * 8;
            int c = cb + tx;
            float v = (c < NCLS) ? p[(size_t)k * NCLS + c] * 0.1f : 0.f;
            tile[ty + j * 8][tx] = v;
        }
        __syncthreads();
#pragma unroll
        for (int j = 0; j < 4; ++j) {
            int c = cb + ty + j * 8;
            int k = kb + tx;
            pT[(size_t)c * KTOT + k] = __float2bfloat16(tile[tx][ty + j * 8]);
        }
    }
}

// ---------------- GEMM1 + sigmoid + routing ----------------
// tile 64(M) x 256(N=one tree), BK=64, 256 thr = 4 waves, each wave 64x64
// (wave wn owns cols [wn*64, wn*64+64)). SINGLE 40KB buffer, plain 2-sync loop
// -> 3-4 blocks/CU (the m97 recipe: TLP over pipelining).
__global__ __launch_bounds__(256, 4) void k_gemm1_route(
        const __hip_bfloat16* __restrict__ xb,
        const __hip_bfloat16* __restrict__ wT,
        __hip_bfloat16* __restrict__ route) {
    __shared__ __align__(16) char smem[40960];   // A 8KB + B 32KB ; epilogue Ds[64][132] f32 = 33.8KB

    int wg = blockIdx.x;                          // 640 blocks
    int sw = (wg & 7) * 80 + (wg >> 3);           // 8 XCD x 80
    const int bm = sw & 63;
    const int tr = sw >> 6;

    const int tid = threadIdx.x;
    const int lane = tid & 63, wid = tid >> 6;    // 4 waves
    const int wn = wid;                           // N-quarter owner
    const int l8 = lane >> 3, c8 = lane & 7;

    f32x4 acc[4][4] = {};

    const __hip_bfloat16* Ag = xb + (size_t)(bm * 64) * FEAT;
    const __hip_bfloat16* Bg = wT + (size_t)tr * NLEAF * FEAT;

    __hip_bfloat16* As = (__hip_bfloat16*)smem;            // [64][64] swizzled
    __hip_bfloat16* Bs = (__hip_bfloat16*)(smem + 8192);   // [256][64] swizzled

    const int NT = FEAT / 64;                     // 16

    for (int t = 0; t < NT; ++t) {
        const int k0 = t * 64;
        // stage A: 2 instrs/wave (8 rows each)
#pragma unroll
        for (int q = 0; q < 2; ++q) {
            int row = (wid * 2 + q) * 8 + l8;
            int ch  = c8 ^ (row & 7);
            load_lds16(Ag + (size_t)row * FEAT + k0 + ch * 8,
                       smem + (wid * 2 + q) * 1024);
        }
        // stage B: 8 instrs/wave
#pragma unroll
        for (int q = 0; q < 8; ++q) {
            int row = (wid * 8 + q) * 8 + l8;
            int ch  = c8 ^ (row & 7);
            load_lds16(Bg + (size_t)row * FEAT + k0 + ch * 8,
                       smem + 8192 + (wid * 8 + q) * 1024);
        }
        __syncthreads();                          // staging visible (vmcnt drain)

#pragma unroll
        for (int ks = 0; ks < 2; ++ks) {
            const int s = ks * 4 + (lane >> 4);
            bf16x8 a[4], b[4];
#pragma unroll
            for (int f = 0; f < 4; ++f) {
                int ra = f * 16 + (lane & 15);                 // A rows 0..63
                int rb = wn * 64 + f * 16 + (lane & 15);       // B rows: this wave's cols
                a[f] = *(const bf16x8*)((const char*)As + ra * 128 + ((s ^ (ra & 7)) << 4));
                b[f] = *(const bf16x8*)((const char*)Bs + rb * 128 + ((s ^ (rb & 7)) << 4));
            }
            __builtin_amdgcn_s_setprio(1);
#pragma unroll
            for (int mf = 0; mf < 4; ++mf)
#pragma unroll
                for (int nf = 0; nf < 4; ++nf)
                    acc[mf][nf] = __builtin_amdgcn_mfma_f32_16x16x32_bf16(
                        a[mf], b[nf], acc[mf][nf], 0, 0, 0);
            __builtin_amdgcn_s_setprio(0);
        }
        __syncthreads();                          // reads retired before next stage
    }

    // ---- epilogue ----
    // phase 1: waves 0,1 write sigmoid of node cols 0..126 to Ds[64][132] fp32
    float* Ds = (float*)smem;
    if (wn < 2) {
#pragma unroll
        for (int mf = 0; mf < 4; ++mf)
#pragma unroll
            for (int nf = 0; nf < 4; ++nf) {
                int col = wn * 64 + nf * 16 + (lane & 15);
                if (col < 127) {
#pragma unroll
                    for (int r = 0; r < 4; ++r) {
                        int row = mf * 16 + (lane >> 4) * 4 + r;
                        float z = acc[mf][nf][r];
                        Ds[row * 132 + col] = 1.f / (1.f + __expf(-z));
                    }
                }
            }
    }
    __syncthreads();
    // phase 2: every acc element with col in [127,254] = level-7 node p=col-127.
    // prefix over levels 0..6 from Ds; level-7 sigmoid from acc; write 2 leaves packed.
    if (wn >= 1) {
#pragma unroll
        for (int mf = 0; mf < 4; ++mf)
#pragma unroll
            for (int nf = 0; nf < 4; ++nf) {
                int col = wn * 64 + nf * 16 + (lane & 15);
                if (col >= 127 && col <= 254) {
                    int pnode = col - 127;
#pragma unroll
                    for (int r = 0; r < 4; ++r) {
                        int row = mf * 16 + (lane >> 4) * 4 + r;
                        float prefix = 1.f;
#pragma unroll
                        for (int l = 0; l < 7; ++l) {
                            int node = (1 << l) - 1 + (pnode >> (7 - l));
                            float v = Ds[row * 132 + node];
                            prefix *= (((pnode >> (6 - l)) & 1) == 0) ? v : (1.f - v);
                        }
                        float wv = 1.f / (1.f + __expf(-acc[mf][nf][r]));
                        union { unsigned int u; __hip_bfloat16 h[2]; } pk;
                        pk.h[0] = __float2bfloat16(prefix * wv);          // leaf 2p (left)
                        pk.h[1] = __float2bfloat16(prefix * (1.f - wv));  // leaf 2p+1
                        int bb = bm * 64 + row;
                        *(unsigned int*)(route + (size_t)bb * KTOT + tr * NLEAF + 2 * pnode) = pk.u;
                    }
                }
            }
    }
}

// ---------------- GEMM2 + clip ----------------
// tile 128x128, grid 256 (1/CU), 512 thr = 8 waves: in-block K-split-2
// (waves 0-3: k<1280, 4-7: k>=1280), each half 2x2 waves of 64x64.
// BK=32, ring-4 per half (4 x 16KB x 2 = 128KB), counted vmcnt 3 tiles deep.
__global__ __launch_bounds__(512, 2) void k_gemm2(
        const __hip_bfloat16* __restrict__ route,
        const __hip_bfloat16* __restrict__ pT,
        float* __restrict__ out) {
    __shared__ __align__(16) char smem[131072];

    int wg = blockIdx.x;                          // 256 blocks
    int sw = (wg & 7) * 32 + (wg >> 3);           // 8 XCD x 32
    const int bm = sw >> 3;
    const int bn = sw & 7;

    const int tid = threadIdx.x;
    const int lane = tid & 63, wid = tid >> 6;
    const int h  = wid >> 2;                      // K half
    const int w2 = wid & 3;
    const int wm = w2 >> 1, wn = w2 & 1;
    const int l4 = lane >> 2, c4 = lane & 3;      // staging decomp (16 rows/instr)

    f32x4 acc[4][4] = {};

    const __hip_bfloat16* Ag = route + (size_t)(bm * 128) * KTOT + h * 1280;
    const __hip_bfloat16* Bg = pT + (size_t)(bn * 128) * KTOT + h * 1280;
    char* bufH = smem + h * 65536;

    const int NT = 1280 / 32;                     // 40 tiles of BK=32 per half

    auto stage = [&](int t) {
        const int k0 = t * 32;
        char* base = bufH + (t & 3) * 16384;      // A 8KB + B 8KB
#pragma unroll
        for (int q = 0; q < 2; ++q) {
            int row = (w2 * 2 + q) * 16 + l4;     // 0..127
            int ch  = c4 ^ ((row >> 1) & 3);
            load_lds16(Ag + (size_t)row * KTOT + k0 + ch * 8,
                       base + (w2 * 2 + q) * 1024);
            load_lds16(Bg + (size_t)row * KTOT + k0 + ch * 8,
                       base + 8192 + (w2 * 2 + q) * 1024);
        }
    };

    stage(0); stage(1); stage(2);                 // 12 per-thread loads in flight

    for (int t = 0; t < NT; ++t) {
        if (t + 3 < NT)       { stage(t + 3); WAITVM(12); }
        else if (t + 3 == NT) { WAITVM(8); }
        else if (t + 2 == NT) { WAITVM(4); }
        else                  { WAITVM(0); }
        BAR();                                    // tile t visible to all 8 waves

        const char* As = bufH + (t & 3) * 16384;
        const char* Bs = As + 8192;
        const int s0 = lane >> 4;                 // 16B chunk 0..3
        bf16x8 a[4], b[4];
#pragma unroll
        for (int f = 0; f < 4; ++f) {
            int ra = wm * 64 + f * 16 + (lane & 15);
            int rb = wn * 64 + f * 16 + (lane & 15);
            a[f] = *(const bf16x8*)(As + ra * 64 + ((s0 ^ ((ra >> 1) & 3)) << 4));
            b[f] = *(const bf16x8*)(Bs + rb * 64 + ((s0 ^ ((rb >> 1) & 3)) << 4));
        }
        WAITLGKM();
        __builtin_amdgcn_s_setprio(1);
#pragma unroll
        for (int mf = 0; mf < 4; ++mf)
#pragma unroll
            for (int nf = 0; nf < 4; ++nf)
                acc[mf][nf] = __builtin_amdgcn_mfma_f32_16x16x32_bf16(
                    a[mf], b[nf], acc[mf][nf], 0, 0, 0);
        __builtin_amdgcn_s_setprio(0);
    }

    // ---- cross-half reduce via LDS, then clip + store ----
    __syncthreads();
    float* R = (float*)smem;                      // 4 quads x [64][65] f32
    if (h == 1) {
#pragma unroll
        for (int mf = 0; mf < 4; ++mf)
#pragma unroll
            for (int nf = 0; nf < 4; ++nf)
#pragma unroll
                for (int r = 0; r < 4; ++r) {
                    int row = mf * 16 + (lane >> 4) * 4 + r;
                    int col = nf * 16 + (lane & 15);
                    R[w2 * 4160 + row * 65 + col] = acc[mf][nf][r];
                }
    }
    __syncthreads();
    if (h == 0) {
#pragma unroll
        for (int mf = 0; mf < 4; ++mf)
#pragma unroll
            for (int nf = 0; nf < 4; ++nf)
#pragma unroll
                for (int r = 0; r < 4; ++r) {
                    int row = mf * 16 + (lane >> 4) * 4 + r;
                    int col = nf * 16 + (lane & 15);
                    float v = acc[mf][nf][r] + R[w2 * 4160 + row * 65 + col];
                    v = fminf(fmaxf(v, 0.f), 1.f);
                    int grow = bm * 128 + wm * 64 + row;
                    int gcol = bn * 128 + wn * 64 + col;
                    if (gcol < NCLS)
                        out[(size_t)grow * NCLS + gcol] = v;
                }
    }
}

extern "C" void kernel_launch(void* const* d_in, const int* in_sizes, int n_in,
                              void* d_out, int out_size, void* d_ws, size_t ws_size,
                              hipStream_t stream) {
    const float* x = (const float*)d_in[0];
    const float* w = (const float*)d_in[1];
    const float* p = (const float*)d_in[2];
    float* out = (float*)d_out;
    char* ws = (char*)d_ws;

    __hip_bfloat16* xb    = (__hip_bfloat16*)(ws + OFF_XB);
    __hip_bfloat16* wT    = (__hip_bfloat16*)(ws + OFF_WT);
    __hip_bfloat16* pT    = (__hip_bfloat16*)(ws + OFF_PT);
    __hip_bfloat16* route = (__hip_bfloat16*)(ws + OFF_RT);

    k_cvt_all<<<9216, 256, 0, stream>>>(x, w, p, xb, wT, pT);
    k_gemm1_route<<<640, 256, 0, stream>>>(xb, wT, route);
    k_gemm2<<<256, 512, 0, stream>>>(route, pT, out);
}

// Round 6
// 98.804 us; speedup vs baseline: 1.0414x; 1.0414x over previous
//
#include <hip/hip_runtime.h>
#include <hip/hip_bf16.h>

// ---- problem constants ----
#define BATCH   4096
#define FEAT    1024
#define NTREES  10
#define NNODES  255
#define NLEAF   256
#define NCLS    1000
#define KTOT    (NTREES*NLEAF) // 2560 = GEMM2 K

typedef __attribute__((ext_vector_type(8))) short  bf16x8;
typedef __attribute__((ext_vector_type(4))) float  f32x4;

// workspace layout (bytes)
#define OFF_XB 0u
#define OFF_WT 8388608u
#define OFF_PT 13631488u
#define OFF_RT 18874368u

#define WAITVM(N) asm volatile("s_waitcnt vmcnt(" #N ")" ::: "memory")
#define WAITLGKM() asm volatile("s_waitcnt lgkmcnt(0)" ::: "memory")
#define BAR() __builtin_amdgcn_s_barrier()

__device__ __forceinline__ void load_lds16(const void* g, void* l) {
    __builtin_amdgcn_global_load_lds(
        (const __attribute__((address_space(1))) unsigned int*)g,
        (__attribute__((address_space(3))) unsigned int*)l, 16, 0, 0);
}

// ---------------- fused conversion kernel ----------------
__global__ void k_cvt_all(const float* __restrict__ x, const float* __restrict__ w,
                          const float* __restrict__ p,
                          __hip_bfloat16* __restrict__ xb,
                          __hip_bfloat16* __restrict__ wT,
                          __hip_bfloat16* __restrict__ pT) {
    __shared__ float tile[32][33];
    const int bid = blockIdx.x;
    const int tid = threadIdx.x;

    if (bid < 4096) {
        int i = bid * 256 + tid;
        float4 v = reinterpret_cast<const float4*>(x)[i];
        union { ushort4 u; __hip_bfloat16 h[4]; } o;
        o.h[0] = __float2bfloat16(v.x);
        o.h[1] = __float2bfloat16(v.y);
        o.h[2] = __float2bfloat16(v.z);
        o.h[3] = __float2bfloat16(v.w);
        reinterpret_cast<ushort4*>(xb)[i] = o.u;
    } else if (bid < 6656) {
        int idx = bid - 4096;              // 2560: t(10) x fb(32) x nb(8)
        int t  = idx >> 8;
        int fb = ((idx >> 3) & 31) * 32;
        int nb = (idx & 7) * 32;
        int tx = tid & 31, ty = tid >> 5;
#pragma unroll
        for (int j = 0; j < 4; ++j) {
            int f = fb + ty + j * 8;
            int n = nb + tx;
            float v = (n < NNODES) ? w[((size_t)t * FEAT + f) * NNODES + n] : 0.f;
            tile[ty + j * 8][tx] = v;
        }
        __syncthreads();
#pragma unroll
        for (int j = 0; j < 4; ++j) {
            int n = nb + ty + j * 8;
            int f = fb + tx;
            wT[((size_t)t * NLEAF + n) * FEAT + f] = __float2bfloat16(tile[tx][ty + j * 8]);
        }
    } else {
        int idx = bid - 6656;              // 2560: kb(80) x cb(32)
        int cb = (idx & 31) * 32;
        int kb = (idx >> 5) * 32;
        int tx = tid & 31, ty = tid >> 5;
#pragma unroll
        for (int j = 0; j < 4; ++j) {
            int k = kb + ty + j * 8;
            int c = cb + tx;
            float v = (c < NCLS) ? p[(size_t)k * NCLS + c] * 0.1f : 0.f;
            tile[ty + j * 8][tx] = v;
        }
        __syncthreads();
#pragma unroll
        for (int j = 0; j < 4; ++j) {
            int c = cb + ty + j * 8;
            int k = kb + tx;
            pT[(size_t)c * KTOT + k] = __float2bfloat16(tile[tx][ty + j * 8]);
        }
    }
}

// ---------------- GEMM1 + sigmoid + routing ----------------
// tile 64(M) x 256(N=one tree), BK=32, 512 thr = 8 waves (2M x 4N, wave 32x64)
// ring-3 x 20KB = 60KB LDS -> 2 blocks/CU (16 waves/CU); counted vmcnt depth-2.
// Loop shape (race-free single barrier): {WAITVM; BAR; stage(t+2); ds_read; lgkm; MFMA}
__global__ __launch_bounds__(512, 4) void k_gemm1_route(
        const __hip_bfloat16* __restrict__ xb,
        const __hip_bfloat16* __restrict__ wT,
        __hip_bfloat16* __restrict__ route) {
    __shared__ __align__(16) char smem[61440];    // 3 x (A 4KB + B 16KB); epilogue Ds[64][132] f32 = 33.8KB

    int wg = blockIdx.x;                          // 640 blocks
    int sw = (wg & 7) * 80 + (wg >> 3);           // 8 XCD x 80
    const int bm = sw & 63;
    const int tr = sw >> 6;

    const int tid = threadIdx.x;
    const int lane = tid & 63, wid = tid >> 6;
    const int wm = wid >> 2, wn = wid & 3;        // 2M x 4N, wave 32x64
    const int l4 = lane >> 2, c4 = lane & 3;      // staging decomp: 16 rows x 4 chunks

    f32x4 acc[2][4] = {};

    const __hip_bfloat16* Ag = xb + (size_t)(bm * 64) * FEAT;
    const __hip_bfloat16* Bg = wT + (size_t)tr * NLEAF * FEAT;

    const int NT = FEAT / 32;                     // 32

    // 3 loads/wave/tile (vmcnt-uniform): 1 A (dup-pair waves w,w+4) + 2 B
    auto stage = [&](int t) {
        const int k0 = t * 32;
        char* base = smem + (t % 3) * 20480;
        {
            int row = (wid & 3) * 16 + l4;        // A rows 0..63; waves w,w+4 duplicate
            int ch  = c4 ^ (row & 3);
            load_lds16(Ag + (size_t)row * FEAT + k0 + ch * 8,
                       base + (wid & 3) * 1024);
        }
#pragma unroll
        for (int q = 0; q < 2; ++q) {
            int row = (wid * 2 + q) * 16 + l4;    // B rows 0..255
            int ch  = c4 ^ (row & 3);
            load_lds16(Bg + (size_t)row * FEAT + k0 + ch * 8,
                       base + 4096 + (wid * 2 + q) * 1024);
        }
    };

    stage(0); stage(1);                           // 6 loads in flight

    for (int t = 0; t < NT; ++t) {
        if (t < NT - 1) { WAITVM(3); }            // tile t landed, t+1 stays in flight
        else           { WAITVM(0); }
        BAR();                                    // all waves' tile-t loads visible
        if (t + 2 < NT) stage(t + 2);             // refill ring (safe: buf (t+2)%3 = (t-1)%3, drained)

        const char* As = smem + (t % 3) * 20480;
        const char* Bs = As + 4096;
        const int s0 = lane >> 4;
        bf16x8 a[2], b[4];
#pragma unroll
        for (int mf = 0; mf < 2; ++mf) {
            int ra = wm * 32 + mf * 16 + (lane & 15);
            a[mf] = *(const bf16x8*)(As + ra * 64 + ((s0 ^ (ra & 3)) << 4));
        }
#pragma unroll
        for (int nf = 0; nf < 4; ++nf) {
            int rb = wn * 64 + nf * 16 + (lane & 15);
            b[nf] = *(const bf16x8*)(Bs + rb * 64 + ((s0 ^ (rb & 3)) << 4));
        }
        WAITLGKM();
        __builtin_amdgcn_s_setprio(1);
#pragma unroll
        for (int mf = 0; mf < 2; ++mf)
#pragma unroll
            for (int nf = 0; nf < 4; ++nf)
                acc[mf][nf] = __builtin_amdgcn_mfma_f32_16x16x32_bf16(
                    a[mf], b[nf], acc[mf][nf], 0, 0, 0);
        __builtin_amdgcn_s_setprio(0);
    }

    __syncthreads();                              // ring dead; reuse as Ds

    // ---- epilogue: sigmoid nodes 0..126 -> Ds; level-7 from regs; write 2 leaves packed
    float* Ds = (float*)smem;                     // [64][132] fp32
    if (wn < 2) {
#pragma unroll
        for (int mf = 0; mf < 2; ++mf)
#pragma unroll
            for (int nf = 0; nf < 4; ++nf) {
                int col = wn * 64 + nf * 16 + (lane & 15);
                if (col < 127) {
#pragma unroll
                    for (int r = 0; r < 4; ++r) {
                        int row = wm * 32 + mf * 16 + (lane >> 4) * 4 + r;
                        float z = acc[mf][nf][r];
                        Ds[row * 132 + col] = 1.f / (1.f + __expf(-z));
                    }
                }
            }
    }
    __syncthreads();
    if (wn >= 1) {
#pragma unroll
        for (int mf = 0; mf < 2; ++mf)
#pragma unroll
            for (int nf = 0; nf < 4; ++nf) {
                int col = wn * 64 + nf * 16 + (lane & 15);
                if (col >= 127 && col <= 254) {
                    int pnode = col - 127;
#pragma unroll
                    for (int r = 0; r < 4; ++r) {
                        int row = wm * 32 + mf * 16 + (lane >> 4) * 4 + r;
                        float prefix = 1.f;
#pragma unroll
                        for (int l = 0; l < 7; ++l) {
                            int node = (1 << l) - 1 + (pnode >> (7 - l));
                            float v = Ds[row * 132 + node];
                            prefix *= (((pnode >> (6 - l)) & 1) == 0) ? v : (1.f - v);
                        }
                        float wv = 1.f / (1.f + __expf(-acc[mf][nf][r]));
                        union { unsigned int u; __hip_bfloat16 h[2]; } pk;
                        pk.h[0] = __float2bfloat16(prefix * wv);
                        pk.h[1] = __float2bfloat16(prefix * (1.f - wv));
                        int bb = bm * 64 + row;
                        *(unsigned int*)(route + (size_t)bb * KTOT + tr * NLEAF + 2 * pnode) = pk.u;
                    }
                }
            }
    }
}

// ---------------- GEMM2 + clip ----------------
// tile 128x128, grid 256 (1/CU), 512 thr = 8 waves: in-block K-split-2,
// each half 2x2 waves of 64x64, BK=32, ring-4 per half (128KB), depth-3 counted vmcnt.
// Race-free loop: {WAITVM; BAR; stage(t+3); ds_read; lgkm; MFMA}
__global__ __launch_bounds__(512, 2) void k_gemm2(
        const __hip_bfloat16* __restrict__ route,
        const __hip_bfloat16* __restrict__ pT,
        float* __restrict__ out) {
    __shared__ __align__(16) char smem[131072];

    int wg = blockIdx.x;                          // 256 blocks
    int sw = (wg & 7) * 32 + (wg >> 3);           // 8 XCD x 32
    const int bm = sw >> 3;
    const int bn = sw & 7;

    const int tid = threadIdx.x;
    const int lane = tid & 63, wid = tid >> 6;
    const int h  = wid >> 2;                      // K half
    const int w2 = wid & 3;
    const int wm = w2 >> 1, wn = w2 & 1;
    const int l4 = lane >> 2, c4 = lane & 3;

    f32x4 acc[4][4] = {};

    const __hip_bfloat16* Ag = route + (size_t)(bm * 128) * KTOT + h * 1280;
    const __hip_bfloat16* Bg = pT + (size_t)(bn * 128) * KTOT + h * 1280;
    char* bufH = smem + h * 65536;

    const int NT = 1280 / 32;                     // 40

    auto stage = [&](int t) {
        const int k0 = t * 32;
        char* base = bufH + (t & 3) * 16384;      // A 8KB + B 8KB
#pragma unroll
        for (int q = 0; q < 2; ++q) {
            int row = (w2 * 2 + q) * 16 + l4;     // 0..127
            int ch  = c4 ^ ((row >> 1) & 3);
            load_lds16(Ag + (size_t)row * KTOT + k0 + ch * 8,
                       base + (w2 * 2 + q) * 1024);
            load_lds16(Bg + (size_t)row * KTOT + k0 + ch * 8,
                       base + 8192 + (w2 * 2 + q) * 1024);
        }
    };

    stage(0); stage(1); stage(2);                 // 12 loads in flight

    for (int t = 0; t < NT; ++t) {
        if (t <= NT - 3)      { WAITVM(8); }      // tile t landed, t+1..t+2 in flight
        else if (t == NT - 2) { WAITVM(4); }
        else                  { WAITVM(0); }
        BAR();
        if (t + 3 < NT) stage(t + 3);             // buf (t+3)&3 = (t-1)&3, drained

        const char* As = bufH + (t & 3) * 16384;
        const char* Bs = As + 8192;
        const int s0 = lane >> 4;
        bf16x8 a[4], b[4];
#pragma unroll
        for (int f = 0; f < 4; ++f) {
            int ra = wm * 64 + f * 16 + (lane & 15);
            int rb = wn * 64 + f * 16 + (lane & 15);
            a[f] = *(const bf16x8*)(As + ra * 64 + ((s0 ^ ((ra >> 1) & 3)) << 4));
            b[f] = *(const bf16x8*)(Bs + rb * 64 + ((s0 ^ ((rb >> 1) & 3)) << 4));
        }
        WAITLGKM();
        __builtin_amdgcn_s_setprio(1);
#pragma unroll
        for (int mf = 0; mf < 4; ++mf)
#pragma unroll
            for (int nf = 0; nf < 4; ++nf)
                acc[mf][nf] = __builtin_amdgcn_mfma_f32_16x16x32_bf16(
                    a[mf], b[nf], acc[mf][nf], 0, 0, 0);
        __builtin_amdgcn_s_setprio(0);
    }

    // ---- cross-half reduce via LDS, then clip + store ----
    __syncthreads();
    float* R = (float*)smem;                      // 4 quads x [64][65] f32
    if (h == 1) {
#pragma unroll
        for (int mf = 0; mf < 4; ++mf)
#pragma unroll
            for (int nf = 0; nf < 4; ++nf)
#pragma unroll
                for (int r = 0; r < 4; ++r) {
                    int row = mf * 16 + (lane >> 4) * 4 + r;
                    int col = nf * 16 + (lane & 15);
                    R[w2 * 4160 + row * 65 + col] = acc[mf][nf][r];
                }
    }
    __syncthreads();
    if (h == 0) {
#pragma unroll
        for (int mf = 0; mf < 4; ++mf)
#pragma unroll
            for (int nf = 0; nf < 4; ++nf)
#pragma unroll
                for (int r = 0; r < 4; ++r) {
                    int row = mf * 16 + (lane >> 4) * 4 + r;
                    int col = nf * 16 + (lane & 15);
                    float v = acc[mf][nf][r] + R[w2 * 4160 + row * 65 + col];
                    v = fminf(fmaxf(v, 0.f), 1.f);
                    int grow = bm * 128 + wm * 64 + row;
                    int gcol = bn * 128 + wn * 64 + col;
                    if (gcol < NCLS)
                        out[(size_t)grow * NCLS + gcol] = v;
                }
    }
}

extern "C" void kernel_launch(void* const* d_in, const int* in_sizes, int n_in,
                              void* d_out, int out_size, void* d_ws, size_t ws_size,
                              hipStream_t stream) {
    const float* x = (const float*)d_in[0];
    const float* w = (const float*)d_in[1];
    const float* p = (const float*)d_in[2];
    float* out = (float*)d_out;
    char* ws = (char*)d_ws;

    __hip_bfloat16* xb    = (__hip_bfloat16*)(ws + OFF_XB);
    __hip_bfloat16* wT    = (__hip_bfloat16*)(ws + OFF_WT);
    __hip_bfloat16* pT    = (__hip_bfloat16*)(ws + OFF_PT);
    __hip_bfloat16* route = (__hip_bfloat16*)(ws + OFF_RT);

    k_cvt_all<<<9216, 256, 0, stream>>>(x, w, p, xb, wT, pT);
    k_gemm1_route<<<640, 512, 0, stream>>>(xb, wT, route);
    k_gemm2<<<256, 512, 0, stream>>>(route, pT, out);
}